// Round 1
// baseline (1387.647 us; speedup 1.0000x reference)
//
#include <hip/hip_runtime.h>
#include <hip/hip_bf16.h>
#include <math.h>

#define NGRAPH 64
#define EPSV 1e-6f

__device__ __forceinline__ unsigned enc_f32(float f){
    unsigned u = __float_as_uint(f);
    return (u & 0x80000000u) ? ~u : (u | 0x80000000u);
}
__device__ __forceinline__ float dec_f32(unsigned u){
    return (u & 0x80000000u) ? __uint_as_float(u & 0x7FFFFFFFu) : __uint_as_float(~u);
}

// ---------------- CSR build ----------------
__global__ void k_hist(const int* __restrict__ tgt, int* __restrict__ cnt, int E){
    int i = blockIdx.x*blockDim.x + threadIdx.x;
    int stride = gridDim.x*blockDim.x;
    for(; i<E; i+=stride) atomicAdd(&cnt[tgt[i]], 1);
}

// single-block exclusive scan over N counts -> row_start[0..N]
__global__ __launch_bounds__(1024) void k_scan(const int* __restrict__ cnt, int* __restrict__ row_start, int N){
    __shared__ int lsum[1024];
    __shared__ int lscan[1024];
    int t = threadIdx.x;
    int chunk = (N + 1023)/1024;
    int beg = t*chunk;
    int end = beg+chunk; if(end>N) end=N;
    int s = 0;
    for(int i=beg;i<end;i++) s += cnt[i];
    lsum[t] = s; lscan[t] = s;
    __syncthreads();
    for(int off=1; off<1024; off<<=1){
        int val = (t>=off)? lscan[t-off] : 0;
        __syncthreads();
        lscan[t] += val;
        __syncthreads();
    }
    int run = lscan[t] - lsum[t];   // exclusive prefix
    for(int i=beg;i<end;i++){ row_start[i] = run; run += cnt[i]; }
    if(t==1023) row_start[N] = lscan[1023];
}

__global__ void k_scatter(const int* __restrict__ src, const int* __restrict__ tgt,
                          const int* __restrict__ row_start, int* __restrict__ cursor,
                          int* __restrict__ sorted_src, int E){
    int i = blockIdx.x*blockDim.x + threadIdx.x;
    int stride = gridDim.x*blockDim.x;
    for(; i<E; i+=stride){
        int tt = tgt[i];
        int pos = row_start[tt] + atomicAdd(&cursor[tt], 1);
        sorted_src[pos] = src[i];
    }
}

// ---------------- per-layer node transform ----------------
// u = x @ fw[:di], v = x @ fw[di:], s1 = x . ww[:di], s2 = x . ww[di:]
// one wave per node; block = 256 (4 waves); fw/ww staged in LDS
__global__ __launch_bounds__(256) void k_node_transform(
    const float* __restrict__ x, const float* __restrict__ fw,
    const float* __restrict__ ww,
    float* __restrict__ u, float* __restrict__ v,
    float* __restrict__ s1, float* __restrict__ s2,
    int N, int di, int d_o)
{
    __shared__ float lfw[128*64];
    __shared__ float lww[128];
    int t = threadIdx.x;
    int tot = 2*di*d_o;
    for(int i=t;i<tot;i+=256) lfw[i]=fw[i];
    for(int i=t;i<2*di;i+=256) lww[i]=ww[i];
    __syncthreads();
    int lane = t & 63;
    int wid  = t >> 6;
    int gw = blockIdx.x*4 + wid;
    int nwaves = gridDim.x*4;
    int c = (lane < d_o) ? lane : 0;
    for(int n=gw; n<N; n+=nwaves){
        float px = (lane<di)? x[(size_t)n*di + lane] : 0.f;
        float p1 = (lane<di)? px*lww[lane]      : 0.f;
        float p2 = (lane<di)? px*lww[di+lane]   : 0.f;
        for(int off=32; off>0; off>>=1){
            p1 += __shfl_xor(p1, off);
            p2 += __shfl_xor(p2, off);
        }
        float ua=0.f, va=0.f;
        for(int k=0;k<di;k++){
            float xk = __shfl(px, k);
            ua = fmaf(xk, lfw[k*d_o + c], ua);
            va = fmaf(xk, lfw[(di+k)*d_o + c], va);
        }
        if(lane < d_o){
            u[(size_t)n*d_o + c] = ua;
            v[(size_t)n*d_o + c] = va;
        }
        if(lane == 0){ s1[n]=p1; s2[n]=p2; }
    }
}

// ---------------- global edge max ----------------
__global__ void k_edge_max(const int* __restrict__ src, const int* __restrict__ tgt,
                           const float* __restrict__ s1, const float* __restrict__ s2,
                           unsigned* __restrict__ amax_enc, int E){
    int i = blockIdx.x*blockDim.x + threadIdx.x;
    int stride = gridDim.x*blockDim.x;
    float m = -3.4e38f;
    for(; i<E; i+=stride){
        float a = s1[src[i]] + s2[tgt[i]];
        m = fmaxf(m, a);
    }
    for(int off=32; off>0; off>>=1) m = fmaxf(m, __shfl_xor(m, off));
    if((threadIdx.x & 63)==0) atomicMax(amax_enc, enc_f32(m));
}

// ---------------- edge softmax + aggregate (CSR, wave per node) ----------------
__global__ __launch_bounds__(256) void k_aggregate(
    const int* __restrict__ row_start, const int* __restrict__ sorted_src,
    const float* __restrict__ u, const float* __restrict__ v,
    const float* __restrict__ s1, const float* __restrict__ s2,
    const float* __restrict__ fb, const float* __restrict__ wb,
    const unsigned* __restrict__ amax_enc,
    float* __restrict__ xout, int N, int d_o)
{
    float wbv  = wb[0];
    float amax = dec_f32(*amax_enc) + wbv;   // max over a = max(s1+s2) + wb
    int lane = threadIdx.x & 63;
    int wid  = threadIdx.x >> 6;
    int gw = blockIdx.x*4 + wid;
    int nwaves = gridDim.x*4;
    int c = (lane < d_o)? lane : 0;
    float fbc = fb[c];
    for(int n=gw; n<N; n+=nwaves){
        float vn  = v[(size_t)n*d_o + c];
        float s2n = s2[n];
        int beg = row_start[n], end = row_start[n+1];
        float acc = 0.f, den = 0.f;
        for(int idx=beg; idx<end; idx++){
            int s = sorted_src[idx];
            float p = __expf(s1[s] + s2n + wbv - amax);
            den += p;
            acc += p * fmaxf(u[(size_t)s*d_o + c] + vn + fbc, 0.f);
        }
        if(lane < d_o) xout[(size_t)n*d_o + c] = acc / (den + EPSV);
    }
}

// ---------------- graph pooling (LDS-binned segment sum) ----------------
__global__ __launch_bounds__(1024) void k_pool(const float* __restrict__ x, const int* __restrict__ gid,
                        float* __restrict__ g, int N){
    __shared__ float bins[64*64];
    int t = threadIdx.x;
    for(int i=t;i<4096;i+=1024) bins[i]=0.f;
    __syncthreads();
    int lane = t & 63, wid = t>>6;
    int gw = blockIdx.x*16 + wid;
    int nwaves = gridDim.x*16;
    for(int n=gw; n<N; n+=nwaves){
        int gi = gid[n];
        atomicAdd(&bins[gi*64 + lane], x[(size_t)n*64 + lane]);
    }
    __syncthreads();
    for(int i=t;i<4096;i+=1024){
        float b = bins[i];
        if(b != 0.f) atomicAdd(&g[i], b);
    }
}

// ---------------- tiny MLP head ----------------
__global__ __launch_bounds__(1024) void k_mlp(const float* __restrict__ g,
        const float* __restrict__ mw0, const float* __restrict__ mb0,
        const float* __restrict__ mw1, const float* __restrict__ mb1,
        float* __restrict__ out){
    __shared__ float lg[64*64];
    __shared__ float hid[64*32];
    int t = threadIdx.x;
    for(int i=t;i<4096;i+=1024) lg[i]=g[i];
    __syncthreads();
    for(int i=t;i<2048;i+=1024){
        int r = i>>5, h = i&31;
        float a = mb0[h];
        for(int k=0;k<64;k++) a = fmaf(lg[r*64+k], mw0[k*32+h], a);
        hid[i] = fmaxf(a, 0.f);
    }
    __syncthreads();
    for(int i=t;i<640;i+=1024){
        int r = i/10, j = i%10;
        float a = mb1[j];
        for(int h=0;h<32;h++) a = fmaf(hid[r*32+h], mw1[h*10+j], a);
        out[i] = a;
    }
}

extern "C" void kernel_launch(void* const* d_in, const int* in_sizes, int n_in,
                              void* d_out, int out_size, void* d_ws, size_t ws_size,
                              hipStream_t stream){
    const float* x   = (const float*)d_in[0];
    const int*   src = (const int*)d_in[1];
    const int*   tgt = (const int*)d_in[2];
    const int*   gid = (const int*)d_in[3];
    const float* fw[3] = {(const float*)d_in[4],  (const float*)d_in[8],  (const float*)d_in[12]};
    const float* fb[3] = {(const float*)d_in[5],  (const float*)d_in[9],  (const float*)d_in[13]};
    const float* ww[3] = {(const float*)d_in[6],  (const float*)d_in[10], (const float*)d_in[14]};
    const float* wb[3] = {(const float*)d_in[7],  (const float*)d_in[11], (const float*)d_in[15]};
    const float* mw0 = (const float*)d_in[16];
    const float* mb0 = (const float*)d_in[17];
    const float* mw1 = (const float*)d_in[18];
    const float* mb1 = (const float*)d_in[19];
    float* out = (float*)d_out;

    const int N = in_sizes[3];   // graph_ids length
    const int E = in_sizes[1];   // src length

    char* ws = (char*)d_ws;
    size_t off = 0;
    auto alloc = [&](size_t bytes)->char*{
        char* p = ws + off;
        off += (bytes + 255) & ~(size_t)255;
        return p;
    };
    int*      cnt        = (int*)     alloc((size_t)N*4);
    int*      cursor     = (int*)     alloc((size_t)N*4);
    int*      row_start  = (int*)     alloc((size_t)(N+1)*4);
    int*      sorted_src = (int*)     alloc((size_t)E*4);
    float*    s1         = (float*)   alloc((size_t)N*4);
    float*    s2         = (float*)   alloc((size_t)N*4);
    float*    u          = (float*)   alloc((size_t)N*64*4);
    float*    v          = (float*)   alloc((size_t)N*64*4);
    float*    xA         = (float*)   alloc((size_t)N*64*4);
    float*    xB         = (float*)   alloc((size_t)N*64*4);
    unsigned* amax       = (unsigned*)alloc(3*4);
    float*    g          = (float*)   alloc(4096*4);

    hipMemsetAsync(cnt,    0, (size_t)N*4, stream);
    hipMemsetAsync(cursor, 0, (size_t)N*4, stream);
    hipMemsetAsync(amax,   0, 12, stream);
    hipMemsetAsync(g,      0, 4096*4, stream);

    k_hist   <<<2048,256,0,stream>>>(tgt, cnt, E);
    k_scan   <<<1,  1024,0,stream>>>(cnt, row_start, N);
    k_scatter<<<2048,256,0,stream>>>(src, tgt, row_start, cursor, sorted_src, E);

    const int DI[3] = {64,32,64};
    const int DO[3] = {32,64,64};
    const float* xin = x;
    float* xout_bufs[3] = {xA, xB, xA};
    for(int l=0;l<3;l++){
        k_node_transform<<<2048,256,0,stream>>>(xin, fw[l], ww[l], u, v, s1, s2, N, DI[l], DO[l]);
        k_edge_max      <<<1024,256,0,stream>>>(src, tgt, s1, s2, &amax[l], E);
        k_aggregate     <<<2048,256,0,stream>>>(row_start, sorted_src, u, v, s1, s2,
                                                fb[l], wb[l], &amax[l], xout_bufs[l], N, DO[l]);
        xin = xout_bufs[l];
    }
    k_pool<<<128,1024,0,stream>>>(xin, gid, g, N);
    k_mlp <<<1,  1024,0,stream>>>(g, mw0, mb0, mw1, mb1, out);
}

// Round 2
// 1036.527 us; speedup vs baseline: 1.3387x; 1.3387x over previous
//
#include <hip/hip_runtime.h>
#include <hip/hip_bf16.h>
#include <math.h>

#define NGRAPH 64
#define EPSV 1e-6f

__device__ __forceinline__ unsigned enc_f32(float f){
    unsigned u = __float_as_uint(f);
    return (u & 0x80000000u) ? ~u : (u | 0x80000000u);
}
__device__ __forceinline__ float dec_f32(unsigned u){
    return (u & 0x80000000u) ? __uint_as_float(u & 0x7FFFFFFFu) : __uint_as_float(~u);
}

// ---------------- CSR build ----------------
__global__ void k_hist(const int* __restrict__ tgt, int* __restrict__ cnt, int E){
    int i = blockIdx.x*blockDim.x + threadIdx.x;
    int stride = gridDim.x*blockDim.x;
    for(; i<E; i+=stride) atomicAdd(&cnt[tgt[i]], 1);
}

// multi-block scan: (1) per-block sums, (2) 1-block scan of block sums, (3) per-block rescan+offset
__global__ __launch_bounds__(256) void k_scan1(const int* __restrict__ cnt, int* __restrict__ bsum, int N){
    __shared__ int red[256];
    int t = threadIdx.x;
    int i = blockIdx.x*256 + t;
    int v = (i<N) ? cnt[i] : 0;
    red[t] = v; __syncthreads();
    for(int off=128; off>0; off>>=1){
        if(t<off) red[t] += red[t+off];
        __syncthreads();
    }
    if(t==0) bsum[blockIdx.x] = red[0];
}

__global__ __launch_bounds__(512) void k_scan2(int* __restrict__ bsum, int nb){
    __shared__ int s[512];
    int t = threadIdx.x;
    int v = (t<nb) ? bsum[t] : 0;
    s[t] = v; __syncthreads();
    for(int off=1; off<512; off<<=1){
        int a = (t>=off) ? s[t-off] : 0;
        __syncthreads();
        s[t] += a;
        __syncthreads();
    }
    if(t<nb) bsum[t] = s[t] - v;   // exclusive prefix of block sums
}

__global__ __launch_bounds__(256) void k_scan3(const int* __restrict__ cnt, const int* __restrict__ bsum,
                                               int* __restrict__ row_start, int N){
    __shared__ int s[256];
    int t = threadIdx.x;
    int i = blockIdx.x*256 + t;
    int v = (i<N) ? cnt[i] : 0;
    s[t] = v; __syncthreads();
    for(int off=1; off<256; off<<=1){
        int a = (t>=off) ? s[t-off] : 0;
        __syncthreads();
        s[t] += a;
        __syncthreads();
    }
    int ex = s[t] - v + bsum[blockIdx.x];
    if(i<N) row_start[i] = ex;
    if(i==N-1) row_start[N] = ex + v;
}

__global__ void k_scatter(const int* __restrict__ src, const int* __restrict__ tgt,
                          const int* __restrict__ row_start, int* __restrict__ cursor,
                          int* __restrict__ sorted_src, int E){
    int i = blockIdx.x*blockDim.x + threadIdx.x;
    int stride = gridDim.x*blockDim.x;
    for(; i<E; i+=stride){
        int tt = tgt[i];
        int pos = row_start[tt] + atomicAdd(&cursor[tt], 1);
        sorted_src[pos] = src[i];
    }
}

// ---------------- per-layer node transform ----------------
// lane-per-node, x row in registers (fully static unroll), weights via uniform
// scalar loads (compiler emits s_load for uniform addr). Zero DS traffic.
template<int DI, int DO>
__global__ __launch_bounds__(256) void k_node_transform_t(
    const float* __restrict__ x, const float* __restrict__ fw,
    const float* __restrict__ ww,
    float* __restrict__ u, float* __restrict__ v,
    float* __restrict__ s1, float* __restrict__ s2, int N)
{
    int n = blockIdx.x*256 + threadIdx.x;
    if(n >= N) return;
    float xr[DI];
    #pragma unroll
    for(int k4=0;k4<DI/4;k4++){
        float4 t = *reinterpret_cast<const float4*>(&x[(size_t)n*DI + k4*4]);
        xr[k4*4+0]=t.x; xr[k4*4+1]=t.y; xr[k4*4+2]=t.z; xr[k4*4+3]=t.w;
    }
    // attention scalars
    float p1=0.f, p2=0.f;
    #pragma unroll
    for(int k=0;k<DI;k++){
        p1 = fmaf(xr[k], ww[k],    p1);
        p2 = fmaf(xr[k], ww[DI+k], p2);
    }
    s1[n] = p1; s2[n] = p2;
    // u = x @ fw_top
    float acc[DO];
    #pragma unroll
    for(int c=0;c<DO;c++) acc[c]=0.f;
    #pragma unroll
    for(int k=0;k<DI;k++){
        float xk = xr[k];
        #pragma unroll
        for(int c=0;c<DO;c++) acc[c] = fmaf(xk, fw[k*DO+c], acc[c]);
    }
    #pragma unroll
    for(int c4=0;c4<DO/4;c4++)
        *reinterpret_cast<float4*>(&u[(size_t)n*DO + c4*4]) =
            make_float4(acc[c4*4],acc[c4*4+1],acc[c4*4+2],acc[c4*4+3]);
    // v = x @ fw_bot
    #pragma unroll
    for(int c=0;c<DO;c++) acc[c]=0.f;
    #pragma unroll
    for(int k=0;k<DI;k++){
        float xk = xr[k];
        #pragma unroll
        for(int c=0;c<DO;c++) acc[c] = fmaf(xk, fw[(DI+k)*DO+c], acc[c]);
    }
    #pragma unroll
    for(int c4=0;c4<DO/4;c4++)
        *reinterpret_cast<float4*>(&v[(size_t)n*DO + c4*4]) =
            make_float4(acc[c4*4],acc[c4*4+1],acc[c4*4+2],acc[c4*4+3]);
}

// ---------------- global edge max ----------------
__global__ void k_edge_max(const int* __restrict__ src, const int* __restrict__ tgt,
                           const float* __restrict__ s1, const float* __restrict__ s2,
                           unsigned* __restrict__ amax_enc, int E){
    int i = blockIdx.x*blockDim.x + threadIdx.x;
    int stride = gridDim.x*blockDim.x;
    float m = -3.4e38f;
    for(; i<E; i+=stride){
        float a = s1[src[i]] + s2[tgt[i]];
        m = fmaxf(m, a);
    }
    for(int off=32; off>0; off>>=1) m = fmaxf(m, __shfl_xor(m, off));
    if((threadIdx.x & 63)==0) atomicMax(amax_enc, enc_f32(m));
}

// ---------------- edge softmax + aggregate (CSR, wave per node) ----------------
__global__ __launch_bounds__(256) void k_aggregate(
    const int* __restrict__ row_start, const int* __restrict__ sorted_src,
    const float* __restrict__ u, const float* __restrict__ v,
    const float* __restrict__ s1, const float* __restrict__ s2,
    const float* __restrict__ fb, const float* __restrict__ wb,
    const unsigned* __restrict__ amax_enc,
    float* __restrict__ xout, int N, int d_o)
{
    float wbv  = wb[0];
    float amax = dec_f32(*amax_enc) + wbv;
    int lane = threadIdx.x & 63;
    int wid  = threadIdx.x >> 6;
    int gw = blockIdx.x*4 + wid;
    int nwaves = gridDim.x*4;
    int c = (lane < d_o)? lane : 0;
    float fbc = fb[c];
    for(int n=gw; n<N; n+=nwaves){
        float vn  = v[(size_t)n*d_o + c];
        float s2n = s2[n];
        int beg = row_start[n], end = row_start[n+1];
        float acc = 0.f, den = 0.f;
        for(int idx=beg; idx<end; idx++){
            int s = sorted_src[idx];
            float p = __expf(s1[s] + s2n + wbv - amax);
            den += p;
            acc += p * fmaxf(u[(size_t)s*d_o + c] + vn + fbc, 0.f);
        }
        if(lane < d_o) xout[(size_t)n*d_o + c] = acc / (den + EPSV);
    }
}

// ---------------- graph pooling (LDS-binned segment sum) ----------------
__global__ __launch_bounds__(1024) void k_pool(const float* __restrict__ x, const int* __restrict__ gid,
                        float* __restrict__ g, int N){
    __shared__ float bins[64*64];
    int t = threadIdx.x;
    for(int i=t;i<4096;i+=1024) bins[i]=0.f;
    __syncthreads();
    int lane = t & 63, wid = t>>6;
    int gw = blockIdx.x*16 + wid;
    int nwaves = gridDim.x*16;
    for(int n=gw; n<N; n+=nwaves){
        int gi = gid[n];
        atomicAdd(&bins[gi*64 + lane], x[(size_t)n*64 + lane]);
    }
    __syncthreads();
    for(int i=t;i<4096;i+=1024){
        float b = bins[i];
        if(b != 0.f) atomicAdd(&g[i], b);
    }
}

// ---------------- tiny MLP head ----------------
__global__ __launch_bounds__(1024) void k_mlp(const float* __restrict__ g,
        const float* __restrict__ mw0, const float* __restrict__ mb0,
        const float* __restrict__ mw1, const float* __restrict__ mb1,
        float* __restrict__ out){
    __shared__ float lg[64*64];
    __shared__ float hid[64*32];
    int t = threadIdx.x;
    for(int i=t;i<4096;i+=1024) lg[i]=g[i];
    __syncthreads();
    for(int i=t;i<2048;i+=1024){
        int r = i>>5, h = i&31;
        float a = mb0[h];
        for(int k=0;k<64;k++) a = fmaf(lg[r*64+k], mw0[k*32+h], a);
        hid[i] = fmaxf(a, 0.f);
    }
    __syncthreads();
    for(int i=t;i<640;i+=1024){
        int r = i/10, j = i%10;
        float a = mb1[j];
        for(int h=0;h<32;h++) a = fmaf(hid[r*32+h], mw1[h*10+j], a);
        out[i] = a;
    }
}

extern "C" void kernel_launch(void* const* d_in, const int* in_sizes, int n_in,
                              void* d_out, int out_size, void* d_ws, size_t ws_size,
                              hipStream_t stream){
    const float* x   = (const float*)d_in[0];
    const int*   src = (const int*)d_in[1];
    const int*   tgt = (const int*)d_in[2];
    const int*   gid = (const int*)d_in[3];
    const float* fw[3] = {(const float*)d_in[4],  (const float*)d_in[8],  (const float*)d_in[12]};
    const float* fb[3] = {(const float*)d_in[5],  (const float*)d_in[9],  (const float*)d_in[13]};
    const float* ww[3] = {(const float*)d_in[6],  (const float*)d_in[10], (const float*)d_in[14]};
    const float* wb[3] = {(const float*)d_in[7],  (const float*)d_in[11], (const float*)d_in[15]};
    const float* mw0 = (const float*)d_in[16];
    const float* mb0 = (const float*)d_in[17];
    const float* mw1 = (const float*)d_in[18];
    const float* mb1 = (const float*)d_in[19];
    float* out = (float*)d_out;

    const int N = in_sizes[3];
    const int E = in_sizes[1];
    const int NB = (N + 255)/256;     // scan blocks (391 for N=100000)

    char* ws = (char*)d_ws;
    size_t off = 0;
    auto alloc = [&](size_t bytes)->char*{
        char* p = ws + off;
        off += (bytes + 255) & ~(size_t)255;
        return p;
    };
    int*      cnt        = (int*)     alloc((size_t)N*4);
    int*      cursor     = (int*)     alloc((size_t)N*4);
    int*      row_start  = (int*)     alloc((size_t)(N+1)*4);
    int*      sorted_src = (int*)     alloc((size_t)E*4);
    float*    s1         = (float*)   alloc((size_t)N*4);
    float*    s2         = (float*)   alloc((size_t)N*4);
    float*    u          = (float*)   alloc((size_t)N*64*4);
    float*    v          = (float*)   alloc((size_t)N*64*4);
    float*    xA         = (float*)   alloc((size_t)N*64*4);
    float*    xB         = (float*)   alloc((size_t)N*64*4);
    unsigned* amax       = (unsigned*)alloc(3*4);
    float*    g          = (float*)   alloc(4096*4);
    int*      bsum       = (int*)     alloc(512*4);

    hipMemsetAsync(cnt,    0, (size_t)N*4, stream);
    hipMemsetAsync(cursor, 0, (size_t)N*4, stream);
    hipMemsetAsync(amax,   0, 12, stream);
    hipMemsetAsync(g,      0, 4096*4, stream);

    k_hist   <<<2048,256,0,stream>>>(tgt, cnt, E);
    k_scan1  <<<NB, 256,0,stream>>>(cnt, bsum, N);
    k_scan2  <<<1,  512,0,stream>>>(bsum, NB);
    k_scan3  <<<NB, 256,0,stream>>>(cnt, bsum, row_start, N);
    k_scatter<<<2048,256,0,stream>>>(src, tgt, row_start, cursor, sorted_src, E);

    const int grid_n = NB;

    // layer 0: 64 -> 32
    k_node_transform_t<64,32><<<grid_n,256,0,stream>>>(x, fw[0], ww[0], u, v, s1, s2, N);
    k_edge_max<<<1024,256,0,stream>>>(src, tgt, s1, s2, &amax[0], E);
    k_aggregate<<<2048,256,0,stream>>>(row_start, sorted_src, u, v, s1, s2, fb[0], wb[0], &amax[0], xA, N, 32);
    // layer 1: 32 -> 64
    k_node_transform_t<32,64><<<grid_n,256,0,stream>>>(xA, fw[1], ww[1], u, v, s1, s2, N);
    k_edge_max<<<1024,256,0,stream>>>(src, tgt, s1, s2, &amax[1], E);
    k_aggregate<<<2048,256,0,stream>>>(row_start, sorted_src, u, v, s1, s2, fb[1], wb[1], &amax[1], xB, N, 64);
    // layer 2: 64 -> 64
    k_node_transform_t<64,64><<<grid_n,256,0,stream>>>(xB, fw[2], ww[2], u, v, s1, s2, N);
    k_edge_max<<<1024,256,0,stream>>>(src, tgt, s1, s2, &amax[2], E);
    k_aggregate<<<2048,256,0,stream>>>(row_start, sorted_src, u, v, s1, s2, fb[2], wb[2], &amax[2], xA, N, 64);

    k_pool<<<128,1024,0,stream>>>(xA, gid, g, N);
    k_mlp <<<1,  1024,0,stream>>>(g, mw0, mb0, mw1, mb1, out);
}

// Round 3
// 793.308 us; speedup vs baseline: 1.7492x; 1.3066x over previous
//
#include <hip/hip_runtime.h>
#include <hip/hip_bf16.h>
#include <math.h>

#define NGRAPH 64
#define EPSV 1e-6f

__device__ __forceinline__ unsigned enc_f32(float f){
    unsigned u = __float_as_uint(f);
    return (u & 0x80000000u) ? ~u : (u | 0x80000000u);
}
__device__ __forceinline__ float dec_f32(unsigned u){
    return (u & 0x80000000u) ? __uint_as_float(u & 0x7FFFFFFFu) : __uint_as_float(~u);
}

// ---------------- CSR build ----------------
__global__ void k_hist(const int* __restrict__ tgt, int* __restrict__ cnt, int E){
    int i = blockIdx.x*blockDim.x + threadIdx.x;
    int stride = gridDim.x*blockDim.x;
    for(; i<E; i+=stride) atomicAdd(&cnt[tgt[i]], 1);
}

__global__ __launch_bounds__(256) void k_scan1(const int* __restrict__ cnt, int* __restrict__ bsum, int N){
    __shared__ int red[256];
    int t = threadIdx.x;
    int i = blockIdx.x*256 + t;
    int v = (i<N) ? cnt[i] : 0;
    red[t] = v; __syncthreads();
    for(int off=128; off>0; off>>=1){
        if(t<off) red[t] += red[t+off];
        __syncthreads();
    }
    if(t==0) bsum[blockIdx.x] = red[0];
}

__global__ __launch_bounds__(512) void k_scan2(int* __restrict__ bsum, int nb){
    __shared__ int s[512];
    int t = threadIdx.x;
    int v = (t<nb) ? bsum[t] : 0;
    s[t] = v; __syncthreads();
    for(int off=1; off<512; off<<=1){
        int a = (t>=off) ? s[t-off] : 0;
        __syncthreads();
        s[t] += a;
        __syncthreads();
    }
    if(t<nb) bsum[t] = s[t] - v;   // exclusive prefix of block sums
}

// also initializes cursor[] = row_start[] so scatter needs no memset/extra load
__global__ __launch_bounds__(256) void k_scan3(const int* __restrict__ cnt, const int* __restrict__ bsum,
                                               int* __restrict__ row_start, int* __restrict__ cursor, int N){
    __shared__ int s[256];
    int t = threadIdx.x;
    int i = blockIdx.x*256 + t;
    int v = (i<N) ? cnt[i] : 0;
    s[t] = v; __syncthreads();
    for(int off=1; off<256; off<<=1){
        int a = (t>=off) ? s[t-off] : 0;
        __syncthreads();
        s[t] += a;
        __syncthreads();
    }
    int ex = s[t] - v + bsum[blockIdx.x];
    if(i<N){ row_start[i] = ex; cursor[i] = ex; }
    if(i==N-1) row_start[N] = ex + v;
}

__global__ void k_scatter(const int* __restrict__ src, const int* __restrict__ tgt,
                          int* __restrict__ cursor, int* __restrict__ sorted_src, int E){
    int i = blockIdx.x*blockDim.x + threadIdx.x;
    int stride = gridDim.x*blockDim.x;
    for(; i<E; i+=stride){
        int pos = atomicAdd(&cursor[tgt[i]], 1);
        sorted_src[pos] = src[i];
    }
}

// ---------------- per-layer node transform ----------------
template<int DI, int DO>
__global__ __launch_bounds__(256) void k_node_transform_t(
    const float* __restrict__ x, const float* __restrict__ fw,
    const float* __restrict__ ww,
    float* __restrict__ u, float* __restrict__ v,
    float* __restrict__ s1, float* __restrict__ s2, int N)
{
    int n = blockIdx.x*256 + threadIdx.x;
    if(n >= N) return;
    float xr[DI];
    #pragma unroll
    for(int k4=0;k4<DI/4;k4++){
        float4 t = *reinterpret_cast<const float4*>(&x[(size_t)n*DI + k4*4]);
        xr[k4*4+0]=t.x; xr[k4*4+1]=t.y; xr[k4*4+2]=t.z; xr[k4*4+3]=t.w;
    }
    float p1=0.f, p2=0.f;
    #pragma unroll
    for(int k=0;k<DI;k++){
        p1 = fmaf(xr[k], ww[k],    p1);
        p2 = fmaf(xr[k], ww[DI+k], p2);
    }
    s1[n] = p1; s2[n] = p2;
    float acc[DO];
    #pragma unroll
    for(int c=0;c<DO;c++) acc[c]=0.f;
    #pragma unroll
    for(int k=0;k<DI;k++){
        float xk = xr[k];
        #pragma unroll
        for(int c=0;c<DO;c++) acc[c] = fmaf(xk, fw[k*DO+c], acc[c]);
    }
    #pragma unroll
    for(int c4=0;c4<DO/4;c4++)
        *reinterpret_cast<float4*>(&u[(size_t)n*DO + c4*4]) =
            make_float4(acc[c4*4],acc[c4*4+1],acc[c4*4+2],acc[c4*4+3]);
    #pragma unroll
    for(int c=0;c<DO;c++) acc[c]=0.f;
    #pragma unroll
    for(int k=0;k<DI;k++){
        float xk = xr[k];
        #pragma unroll
        for(int c=0;c<DO;c++) acc[c] = fmaf(xk, fw[(DI+k)*DO+c], acc[c]);
    }
    #pragma unroll
    for(int c4=0;c4<DO/4;c4++)
        *reinterpret_cast<float4*>(&v[(size_t)n*DO + c4*4]) =
            make_float4(acc[c4*4],acc[c4*4+1],acc[c4*4+2],acc[c4*4+3]);
}

// ---------------- global edge max ----------------
__global__ void k_edge_max(const int* __restrict__ src, const int* __restrict__ tgt,
                           const float* __restrict__ s1, const float* __restrict__ s2,
                           unsigned* __restrict__ amax_enc, int E){
    int i = blockIdx.x*blockDim.x + threadIdx.x;
    int stride = gridDim.x*blockDim.x;
    float m = -3.4e38f;
    for(; i<E; i+=stride){
        float a = s1[src[i]] + s2[tgt[i]];
        m = fmaxf(m, a);
    }
    for(int off=32; off>0; off>>=1) m = fmaxf(m, __shfl_xor(m, off));
    if((threadIdx.x & 63)==0) atomicMax(amax_enc, enc_f32(m));
}

// ---------------- edge softmax + aggregate (CSR, wave per node) ----------------
// DO=64: 1 edge group (all 64 lanes = channels). DO=32: 2 edge groups (halves
// of the wave process even/odd edges), combined via shfl_xor(32) at the end.
// Edge loop unrolled x4 for memory-level parallelism (latency-bound fix).
template<int DO>
__global__ __launch_bounds__(256) void k_aggregate_t(
    const int* __restrict__ row_start, const int* __restrict__ sorted_src,
    const float* __restrict__ u, const float* __restrict__ v,
    const float* __restrict__ s1, const float* __restrict__ s2,
    const float* __restrict__ fb,
    const unsigned* __restrict__ amax_enc,
    float* __restrict__ xout, int N)
{
    constexpr int PN = 64 / DO;           // edge groups per wave (1 or 2)
    float amax = dec_f32(*amax_enc);      // wb cancels in the softmax
    int lane = threadIdx.x & 63;
    int wid  = threadIdx.x >> 6;
    int c    = lane & (DO-1);
    int grp  = lane >> (DO==32 ? 5 : 6);
    float fbc = fb[c];
    int gw = blockIdx.x*4 + wid;
    int nwaves = gridDim.x*4;
    for(int n=gw; n<N; n+=nwaves){
        float vn  = v[(size_t)n*DO + c];
        float s2b = s2[n] - amax;
        int beg = row_start[n], end = row_start[n+1];
        float acc = 0.f, den = 0.f;
        int idx = beg + grp;
        for(; idx + 3*PN < end; idx += 4*PN){
            int sA = sorted_src[idx];
            int sB = sorted_src[idx+PN];
            int sC = sorted_src[idx+2*PN];
            int sD = sorted_src[idx+3*PN];
            float aA = s1[sA], aB = s1[sB], aC = s1[sC], aD = s1[sD];
            float uA = u[(size_t)sA*DO+c], uB = u[(size_t)sB*DO+c];
            float uC = u[(size_t)sC*DO+c], uD = u[(size_t)sD*DO+c];
            float pA = __expf(aA + s2b), pB = __expf(aB + s2b);
            float pC = __expf(aC + s2b), pD = __expf(aD + s2b);
            den += (pA+pB)+(pC+pD);
            acc = fmaf(pA, fmaxf(uA+vn+fbc,0.f), acc);
            acc = fmaf(pB, fmaxf(uB+vn+fbc,0.f), acc);
            acc = fmaf(pC, fmaxf(uC+vn+fbc,0.f), acc);
            acc = fmaf(pD, fmaxf(uD+vn+fbc,0.f), acc);
        }
        for(; idx < end; idx += PN){
            int s = sorted_src[idx];
            float p = __expf(s1[s] + s2b);
            den += p;
            acc = fmaf(p, fmaxf(u[(size_t)s*DO+c]+vn+fbc,0.f), acc);
        }
        if(PN==2){
            acc += __shfl_xor(acc, 32);
            den += __shfl_xor(den, 32);
        }
        if(lane < DO) xout[(size_t)n*DO + c] = acc / (den + EPSV);
    }
}

// ---------------- graph pooling ----------------
__global__ __launch_bounds__(1024) void k_pool(const float* __restrict__ x, const int* __restrict__ gid,
                        float* __restrict__ g, int N){
    __shared__ float bins[64*64];
    int t = threadIdx.x;
    for(int i=t;i<4096;i+=1024) bins[i]=0.f;
    __syncthreads();
    int lane = t & 63, wid = t>>6;
    int gw = blockIdx.x*16 + wid;
    int nwaves = gridDim.x*16;
    for(int n=gw; n<N; n+=nwaves){
        int gi = gid[n];
        atomicAdd(&bins[gi*64 + lane], x[(size_t)n*64 + lane]);
    }
    __syncthreads();
    for(int i=t;i<4096;i+=1024){
        float b = bins[i];
        if(b != 0.f) atomicAdd(&g[i], b);
    }
}

// ---------------- tiny MLP head ----------------
__global__ __launch_bounds__(1024) void k_mlp(const float* __restrict__ g,
        const float* __restrict__ mw0, const float* __restrict__ mb0,
        const float* __restrict__ mw1, const float* __restrict__ mb1,
        float* __restrict__ out){
    __shared__ float lg[64*64];
    __shared__ float hid[64*32];
    int t = threadIdx.x;
    for(int i=t;i<4096;i+=1024) lg[i]=g[i];
    __syncthreads();
    for(int i=t;i<2048;i+=1024){
        int r = i>>5, h = i&31;
        float a = mb0[h];
        for(int k=0;k<64;k++) a = fmaf(lg[r*64+k], mw0[k*32+h], a);
        hid[i] = fmaxf(a, 0.f);
    }
    __syncthreads();
    for(int i=t;i<640;i+=1024){
        int r = i/10, j = i%10;
        float a = mb1[j];
        for(int h=0;h<32;h++) a = fmaf(hid[r*32+h], mw1[h*10+j], a);
        out[i] = a;
    }
}

extern "C" void kernel_launch(void* const* d_in, const int* in_sizes, int n_in,
                              void* d_out, int out_size, void* d_ws, size_t ws_size,
                              hipStream_t stream){
    const float* x   = (const float*)d_in[0];
    const int*   src = (const int*)d_in[1];
    const int*   tgt = (const int*)d_in[2];
    const int*   gid = (const int*)d_in[3];
    const float* fw[3] = {(const float*)d_in[4],  (const float*)d_in[8],  (const float*)d_in[12]};
    const float* fb[3] = {(const float*)d_in[5],  (const float*)d_in[9],  (const float*)d_in[13]};
    const float* ww[3] = {(const float*)d_in[6],  (const float*)d_in[10], (const float*)d_in[14]};
    const float* mw0 = (const float*)d_in[16];
    const float* mb0 = (const float*)d_in[17];
    const float* mw1 = (const float*)d_in[18];
    const float* mb1 = (const float*)d_in[19];
    float* out = (float*)d_out;

    const int N = in_sizes[3];
    const int E = in_sizes[1];
    const int NB = (N + 255)/256;

    char* ws = (char*)d_ws;
    size_t off = 0;
    auto alloc = [&](size_t bytes)->char*{
        char* p = ws + off;
        off += (bytes + 255) & ~(size_t)255;
        return p;
    };
    int*      cnt        = (int*)     alloc((size_t)N*4);
    int*      cursor     = (int*)     alloc((size_t)N*4);
    int*      row_start  = (int*)     alloc((size_t)(N+1)*4);
    int*      sorted_src = (int*)     alloc((size_t)E*4);
    float*    s1         = (float*)   alloc((size_t)N*4);
    float*    s2         = (float*)   alloc((size_t)N*4);
    float*    u          = (float*)   alloc((size_t)N*64*4);
    float*    v          = (float*)   alloc((size_t)N*64*4);
    float*    xA         = (float*)   alloc((size_t)N*64*4);
    float*    xB         = (float*)   alloc((size_t)N*64*4);
    unsigned* amax       = (unsigned*)alloc(3*4);
    float*    g          = (float*)   alloc(4096*4);
    int*      bsum       = (int*)     alloc(512*4);

    hipMemsetAsync(cnt,  0, (size_t)N*4, stream);
    hipMemsetAsync(amax, 0, 12, stream);
    hipMemsetAsync(g,    0, 4096*4, stream);

    k_hist   <<<2048,256,0,stream>>>(tgt, cnt, E);
    k_scan1  <<<NB, 256,0,stream>>>(cnt, bsum, N);
    k_scan2  <<<1,  512,0,stream>>>(bsum, NB);
    k_scan3  <<<NB, 256,0,stream>>>(cnt, bsum, row_start, cursor, N);
    k_scatter<<<2048,256,0,stream>>>(src, tgt, cursor, sorted_src, E);

    // layer 0: 64 -> 32
    k_node_transform_t<64,32><<<NB,256,0,stream>>>(x, fw[0], ww[0], u, v, s1, s2, N);
    k_edge_max<<<1024,256,0,stream>>>(src, tgt, s1, s2, &amax[0], E);
    k_aggregate_t<32><<<2048,256,0,stream>>>(row_start, sorted_src, u, v, s1, s2, fb[0], &amax[0], xA, N);
    // layer 1: 32 -> 64
    k_node_transform_t<32,64><<<NB,256,0,stream>>>(xA, fw[1], ww[1], u, v, s1, s2, N);
    k_edge_max<<<1024,256,0,stream>>>(src, tgt, s1, s2, &amax[1], E);
    k_aggregate_t<64><<<2048,256,0,stream>>>(row_start, sorted_src, u, v, s1, s2, fb[1], &amax[1], xB, N);
    // layer 2: 64 -> 64
    k_node_transform_t<64,64><<<NB,256,0,stream>>>(xB, fw[2], ww[2], u, v, s1, s2, N);
    k_edge_max<<<1024,256,0,stream>>>(src, tgt, s1, s2, &amax[2], E);
    k_aggregate_t<64><<<2048,256,0,stream>>>(row_start, sorted_src, u, v, s1, s2, fb[2], &amax[2], xA, N);

    k_pool<<<128,1024,0,stream>>>(xA, gid, g, N);
    k_mlp <<<1,  1024,0,stream>>>(g, mw0, mb0, mw1, mb1, out);
}